// Round 9
// baseline (326.276 us; speedup 1.0000x reference)
//
#include <hip/hip_runtime.h>

#define HWB   3136
#define HWPAD 3200
#define SPAD  3364   // 58*58 zero-padded spatial

typedef __attribute__((ext_vector_type(8))) short bf16x8;
typedef __attribute__((ext_vector_type(4))) float f32x4;

__device__ __forceinline__ unsigned short f2bf(float f) {
    unsigned u = __float_as_uint(f);
    unsigned r = (u + 0x7fffu + ((u >> 16) & 1u)) >> 16;
    return (unsigned short)r;
}
__device__ __forceinline__ float bf2f(unsigned short h) {
    return __uint_as_float(((unsigned)h) << 16);
}
__device__ __forceinline__ void gl_lds16(const void* g, void* l) {
    __builtin_amdgcn_global_load_lds(
        (const __attribute__((address_space(1))) void*)g,
        (__attribute__((address_space(3))) void*)l, 16, 0, 0);
}

// ---------------------------------------------------------------------------
// Merged prep (one dispatch, 8248 blocks):
//  [0,6272):    x f32 -> xc bf16 (same layout) + xp bf16 (padded ch-last).
//  [6272,7056): p1 -> p1t transpose.  [7056,7312): wpack.
//  [7312,8240): xp border zero.  [8240,8248): zero t5.
// ---------------------------------------------------------------------------
__global__ __launch_bounds__(256) void k_prep(
    const float* __restrict__ x, unsigned short* __restrict__ xc,
    unsigned short* __restrict__ xp,
    const float* __restrict__ p1, const float* __restrict__ cw,
    unsigned short* __restrict__ p1t, unsigned short* __restrict__ wp,
    float* __restrict__ t5)
{
    const int b = blockIdx.x, t = threadIdx.x;
    if (b < 6272) {
        __shared__ unsigned tile[64 * 33];     // dwords = channel pairs
        const int n = b / 196, rem = b - n * 196;
        const int c0 = (rem / 49) * 64, s0 = (rem % 49) * 64;
        const int cp = t >> 3;                 // 0..31 channel pair
        const int sg = (t & 7) * 8;            // s offset within tile

        const float* src = x + ((size_t)(n * 256 + c0 + 2 * cp)) * HWB + s0 + sg;
        unsigned short b0[8], b1[8];
        {
            float4 v0 = *(const float4*)(src);
            float4 v1 = *(const float4*)(src + 4);
            float4 w0 = *(const float4*)(src + HWB);
            float4 w1 = *(const float4*)(src + HWB + 4);
            b0[0] = f2bf(v0.x); b0[1] = f2bf(v0.y); b0[2] = f2bf(v0.z); b0[3] = f2bf(v0.w);
            b0[4] = f2bf(v1.x); b0[5] = f2bf(v1.y); b0[6] = f2bf(v1.z); b0[7] = f2bf(v1.w);
            b1[0] = f2bf(w0.x); b1[1] = f2bf(w0.y); b1[2] = f2bf(w0.z); b1[3] = f2bf(w0.w);
            b1[4] = f2bf(w1.x); b1[5] = f2bf(w1.y); b1[6] = f2bf(w1.z); b1[7] = f2bf(w1.w);
        }
        unsigned short* xcb = xc + ((size_t)(n * 256 + c0 + 2 * cp)) * HWB + s0 + sg;
        *(bf16x8*)xcb = *(const bf16x8*)&b0[0];
        *(bf16x8*)(xcb + HWB) = *(const bf16x8*)&b1[0];
#pragma unroll
        for (int k = 0; k < 8; ++k)
            tile[(sg + k) * 33 + cp] = (unsigned)b0[k] | ((unsigned)b1[k] << 16);
        __syncthreads();
        const int r = t >> 2;                  // 0..63 local s row
        const int cq = (t & 3) * 8;            // dword col base
        unsigned d[8];
#pragma unroll
        for (int j = 0; j < 8; ++j)
            d[j] = tile[r * 33 + cq + j];
        const int s = s0 + r;
        const int sp = s + 2 * (s / 56) + 59;  // (y+1)*58 + (x+1)
        unsigned* dst = (unsigned*)(xp + ((size_t)n * SPAD + sp) * 256 + c0 + 2 * cq);
        *(uint4*)dst = make_uint4(d[0], d[1], d[2], d[3]);
        *(uint4*)(dst + 4) = make_uint4(d[4], d[5], d[6], d[7]);
    } else if (b < 7056) {
        __shared__ unsigned short tile[32][33];
        const int b2 = b - 6272;
        const int h0 = (b2 % 98) * 32, e0 = (b2 / 98) * 32;
        const int lx = t & 31, ly = t >> 5;
#pragma unroll
        for (int it = 0; it < 4; ++it) {
            int lh = ly + it * 8;
            tile[lh][lx] = f2bf(p1[(size_t)(h0 + lh) * 256 + e0 + lx]);
        }
        __syncthreads();
#pragma unroll
        for (int it = 0; it < 4; ++it) {
            int le = ly + it * 8;
            p1t[(size_t)(e0 + le) * HWB + h0 + lx] = tile[lx][le];
        }
    } else if (b < 7312) {
        const int o = b - 7056;
#pragma unroll
        for (int k = t; k < 1152; k += 256) {
            int tap = k >> 7, ci = k & 127;
            wp[(size_t)o * 1152 + k] = f2bf(cw[(size_t)o * 1152 + ci * 9 + tap]);
        }
    } else if (b < 8240) {
        const int bb = b - 7312;
        const int n = bb / 29, xb = bb - n * 29;
        const int idx = xb * 256 + t;
        if (idx < 228 * 32) {
            const int i = idx >> 5, ch = idx & 31;
            int sp;
            if (i < 58)       sp = i;
            else if (i < 116) sp = 3306 + (i - 58);
            else if (i < 172) sp = (i - 115) * 58;
            else              sp = (i - 171) * 58 + 57;
            bf16x8 z = {};
            *(bf16x8*)&xp[((size_t)n * SPAD + sp) * 256 + ch * 8] = z;
        }
    } else {
        float4 z = {0.f, 0.f, 0.f, 0.f};
        *(float4*)&t5[(((b - 8240) * 256) + t) * 4] = z;
    }
}

// ---------------------------------------------------------------------------
// Merged MFMA dispatch (1728 blocks).  Both branches use SWAPPED operands
// (A = the operand whose rows land in the C-fragment row index) so the
// r-index walks the CONTIGUOUS output axis -> vectorized epilogue stores.
//  [0,128):     GEMM1 K=3136 (49 steps), fused t4scale epilogue.
//               A = p1t (e-rows), B = xc (m-rows); t4h stores = ushort4.
//  [128,1728):  grouped 3x3 conv, K=1152, XCD-swizzled, dbuf LDS.
//               A = wpack (oc-rows), B = xp (s-rows); t3cl stores = ushort4.
// ---------------------------------------------------------------------------
__global__ __launch_bounds__(256) void k_mfma(
    const unsigned short* __restrict__ xp, const unsigned short* __restrict__ wp,
    unsigned short* __restrict__ t3cl,
    const unsigned short* __restrict__ xc, const unsigned short* __restrict__ p1t,
    const float* __restrict__ p4, const float* __restrict__ p5,
    unsigned short* __restrict__ t4h, float* __restrict__ t5)
{
    __shared__ short As[2][128 * 64];
    __shared__ short Bs[2][128 * 64];
    const int tid = threadIdx.x;
    const int wave = tid >> 6, lane = tid & 63;
    const int wm = (wave >> 1) * 64, wn = (wave & 1) * 64;
    const int rl = tid >> 3, q = tid & 7;
    const int swq = (q ^ (rl & 7)) * 8;
    const int ldst = rl * 64 + q * 8;
    const int frow = lane & 15, quad = lane >> 4, sw = frow & 7;

    if (blockIdx.x >= 128) {
        // ----- conv: D[oc][s] (wm tiles oc via weights-A, wn tiles s) -----
        const int orig = blockIdx.x - 128;                 // 1600 = 8 * 200
        const int wgid = (orig & 7) * 200 + (orig >> 3);
        const int ng = wgid / 25;
        const int tileS = (wgid - ng * 25) * 128;
        const int n = ng >> 1, g = ng & 1;

        const unsigned short* xpn = xp + (size_t)n * SPAD * 256 + g * 128 + swq;
        const unsigned short* arow[4];
        const unsigned short* brow[4];
#pragma unroll
        for (int p = 0; p < 4; ++p) {
            int s = tileS + p * 32 + rl;
            int sc = s < HWB ? s : HWB - 1;
            int sp = sc + 2 * (sc / 56) + 59;
            arow[p] = xpn + (size_t)sp * 256;
            brow[p] = wp + (size_t)(g * 128 + p * 32 + rl) * 1152 + swq;
        }

        f32x4 acc[4][4] = {};
        int rofW[4], rofX[4];
#pragma unroll
        for (int i = 0; i < 4; ++i) {
            rofW[i] = (wm + i * 16 + frow) * 64;    // weights rows (Bs buffer)
            rofX[i] = (wn + i * 16 + frow) * 64;    // x rows (As buffer)
        }
        {
            const int shift0 = (-59) * 256;
#pragma unroll
            for (int p = 0; p < 4; ++p) {
                gl_lds16(arow[p] + shift0, &As[0][p * 2048 + ldst]);
                gl_lds16(brow[p], &Bs[0][p * 2048 + ldst]);
            }
        }
        __syncthreads();

        int cur = 0;
#pragma unroll
        for (int t = 0; t < 18; ++t) {
            if (t < 17) {
                const int tn = t + 1;
                const int tap = tn >> 1;
                const int shift = ((tap / 3 - 1) * 58 + (tap % 3 - 1)) * 256 + (tn & 1) * 64;
#pragma unroll
                for (int p = 0; p < 4; ++p) {
                    gl_lds16(arow[p] + shift, &As[cur ^ 1][p * 2048 + ldst]);
                    gl_lds16(brow[p] + tn * 64, &Bs[cur ^ 1][p * 2048 + ldst]);
                }
            }
            const short* Ab = As[cur];
            const short* Bb = Bs[cur];
#pragma unroll
            for (int h = 0; h < 2; ++h) {
                bf16x8 af[4], bfr[4];
#pragma unroll
                for (int i = 0; i < 4; ++i)
                    af[i] = *(const bf16x8*)&Bb[rofW[i] + ((h * 4 + quad) ^ sw) * 8];
#pragma unroll
                for (int j = 0; j < 4; ++j)
                    bfr[j] = *(const bf16x8*)&Ab[rofX[j] + ((h * 4 + quad) ^ sw) * 8];
#pragma unroll
                for (int i = 0; i < 4; ++i)
#pragma unroll
                    for (int j = 0; j < 4; ++j)
                        acc[i][j] = __builtin_amdgcn_mfma_f32_16x16x32_bf16(af[i], bfr[j], acc[i][j], 0, 0, 0);
            }
            __syncthreads();
            cur ^= 1;
        }
        // epilogue: lane holds 4 consecutive oc per (i,j) -> ushort4 stores
        unsigned short* ob = t3cl + (size_t)n * HWPAD * 256 + g * 128;
#pragma unroll
        for (int j = 0; j < 4; ++j) {
            const int s = tileS + wn + j * 16 + frow;
            const bool vs = s < HWB;
#pragma unroll
            for (int i = 0; i < 4; ++i) {
                const int oc0 = wm + i * 16 + quad * 4;
                ushort4 o;
                o.x = vs ? f2bf(acc[i][j][0]) : 0;
                o.y = vs ? f2bf(acc[i][j][1]) : 0;
                o.z = vs ? f2bf(acc[i][j][2]) : 0;
                o.w = vs ? f2bf(acc[i][j][3]) : 0;
                *(ushort4*)&ob[(size_t)s * 256 + oc0] = o;
            }
        }
    } else {
        // ----- gemm1: D[e][m] (wm tiles e via p1t-A, wn tiles m) -----
        const int orig = blockIdx.x;                      // 128 = 8 * 16
        const int wgid = (orig & 7) * 16 + (orig >> 3);
        const int tileM = (wgid >> 1) * 128;
        const int tileN = (wgid & 1) * 128;

        const unsigned short* asrc = xc + (size_t)(tileM + rl) * HWB + swq;
        const unsigned short* bsrc = p1t + (size_t)(tileN + rl) * HWB + swq;

        f32x4 acc[4][4] = {};
#pragma unroll
        for (int p = 0; p < 4; ++p) {
            gl_lds16(asrc + (size_t)(p * 32) * HWB, &As[0][p * 2048 + ldst]);
            gl_lds16(bsrc + (size_t)(p * 32) * HWB, &Bs[0][p * 2048 + ldst]);
        }
        __syncthreads();

        int cur = 0;
        for (int i2 = 0; i2 < 49; ++i2) {
            if (i2 + 1 < 49) {
                const int kn = (i2 + 1) * 64;
#pragma unroll
                for (int p = 0; p < 4; ++p) {
                    gl_lds16(asrc + (size_t)(p * 32) * HWB + kn, &As[cur ^ 1][p * 2048 + ldst]);
                    gl_lds16(bsrc + (size_t)(p * 32) * HWB + kn, &Bs[cur ^ 1][p * 2048 + ldst]);
                }
            }
            const short* Ab = As[cur];
            const short* Bb = Bs[cur];
#pragma unroll
            for (int h = 0; h < 2; ++h) {
                bf16x8 af[4], bfr[4];
#pragma unroll
                for (int i = 0; i < 4; ++i)
                    af[i] = *(const bf16x8*)&Bb[(wm + i * 16 + frow) * 64 + ((h * 4 + quad) ^ sw) * 8];
#pragma unroll
                for (int j = 0; j < 4; ++j)
                    bfr[j] = *(const bf16x8*)&Ab[(wn + j * 16 + frow) * 64 + ((h * 4 + quad) ^ sw) * 8];
#pragma unroll
                for (int i = 0; i < 4; ++i)
#pragma unroll
                    for (int j = 0; j < 4; ++j)
                        acc[i][j] = __builtin_amdgcn_mfma_f32_16x16x32_bf16(af[i], bfr[j], acc[i][j], 0, 0, 0);
            }
            __syncthreads();
            cur ^= 1;
        }
        // fused t4scale: lane holds 4 consecutive e per (i,j) -> ushort4;
        // t5[m] partial reduced across quads (shfl 16,32), 1 atomic/lane<16.
#pragma unroll
        for (int j = 0; j < 4; ++j) {
            const int m = tileM + wn + j * 16 + frow;
            const float* p4row = p4 + (size_t)(m & 255) * 256;
            float s = 0.f;
#pragma unroll
            for (int i = 0; i < 4; ++i) {
                const int e0 = tileN + wm + i * 16 + quad * 4;
                float4 p4v = *(const float4*)&p4row[e0];
                float4 p5v = *(const float4*)&p5[e0];
                float t0 = acc[i][j][0] * p4v.x;
                float t1 = acc[i][j][1] * p4v.y;
                float t2 = acc[i][j][2] * p4v.z;
                float t3 = acc[i][j][3] * p4v.w;
                ushort4 o;
                o.x = f2bf(t0); o.y = f2bf(t1); o.z = f2bf(t2); o.w = f2bf(t3);
                *(ushort4*)&t4h[(size_t)m * 256 + e0] = o;
                s += t0 * p5v.x + t1 * p5v.y + t2 * p5v.z + t3 * p5v.w;
            }
            s += __shfl_xor(s, 16);
            s += __shfl_xor(s, 32);
            if (lane < 16) atomicAdd(&t5[m], s);
        }
    }
}

// ---------------------------------------------------------------------------
// BMM: out[n][a][s] = (sum_b t4h[n][a][b] * t3cl[n][s][b]) / 16 + t7[n][s]
// Swapped operands: D[s][a] fragment (wm tiles s via t3cl-A, wn tiles a)
// -> lane holds 4 consecutive s per (i,j) -> float4 stores.
// t7 computed in-kernel from xp row dot t5 (4 ILP chains).
// ---------------------------------------------------------------------------
__global__ __launch_bounds__(256) void k_bmm(
    const unsigned short* __restrict__ t4h, const unsigned short* __restrict__ t3cl,
    const unsigned short* __restrict__ xp, const float* __restrict__ t5,
    float* __restrict__ out)
{
    __shared__ short As[2][128 * 64];
    __shared__ short Bs[2][128 * 64];
    __shared__ float t5s[256];
    __shared__ float t7loc[128];
    const int tid = threadIdx.x;
    const int orig = blockIdx.x;                       // 1600 = 8 * 200
    const int wgid = (orig & 7) * 200 + (orig >> 3);
    const int n = wgid / 50;
    const int rem = wgid - n * 50;
    const int tileA = (rem / 25) * 128;
    const int tileS = (rem % 25) * 128;
    const int wave = tid >> 6, lane = tid & 63;
    const int wm = (wave >> 1) * 64, wn = (wave & 1) * 64;

    const int rl = tid >> 3, q = tid & 7;
    const int swq = (q ^ (rl & 7)) * 8;
    const unsigned short* asrc = t4h + ((size_t)n * 256 + tileA + rl) * 256 + swq;
    const unsigned short* bsrc = t3cl + ((size_t)n * HWPAD + tileS + rl) * 256 + swq;

    f32x4 acc[4][4] = {};
    const int frow = lane & 15, quad = lane >> 4, sw = frow & 7;
    const int ldst = rl * 64 + q * 8;

    t5s[tid] = t5[n * 256 + tid];
#pragma unroll
    for (int p = 0; p < 4; ++p) {
        gl_lds16(asrc + (size_t)(p * 32) * 256, &As[0][p * 2048 + ldst]);
        gl_lds16(bsrc + (size_t)(p * 32) * 256, &Bs[0][p * 2048 + ldst]);
    }
    __syncthreads();   // t5s visible; buf0 staged

    if (tid < 128) {
        const int s = tileS + tid;
        float accv = 0.f;
        if (s < HWB) {
            const int sp = s + 2 * (s / 56) + 59;
            const unsigned short* row = xp + ((size_t)n * SPAD + sp) * 256;
            float p0 = 0.f, p1 = 0.f, p2 = 0.f, p3 = 0.f;
#pragma unroll
            for (int j = 0; j < 32; ++j) {
                bf16x8 v = *(const bf16x8*)(row + j * 8);
                p0 += t5s[j * 8 + 0] * bf2f((unsigned short)v[0]);
                p1 += t5s[j * 8 + 1] * bf2f((unsigned short)v[1]);
                p2 += t5s[j * 8 + 2] * bf2f((unsigned short)v[2]);
                p3 += t5s[j * 8 + 3] * bf2f((unsigned short)v[3]);
                p0 += t5s[j * 8 + 4] * bf2f((unsigned short)v[4]);
                p1 += t5s[j * 8 + 5] * bf2f((unsigned short)v[5]);
                p2 += t5s[j * 8 + 6] * bf2f((unsigned short)v[6]);
                p3 += t5s[j * 8 + 7] * bf2f((unsigned short)v[7]);
            }
            accv = (p0 + p1) + (p2 + p3);
        }
        t7loc[tid] = accv * 0.0625f;
    }

    int cur = 0;
#pragma unroll
    for (int k0 = 0; k0 < 256; k0 += 64) {
        if (k0 < 192) {
            const int kn = k0 + 64;
#pragma unroll
            for (int p = 0; p < 4; ++p) {
                gl_lds16(asrc + (size_t)(p * 32) * 256 + kn, &As[cur ^ 1][p * 2048 + ldst]);
                gl_lds16(bsrc + (size_t)(p * 32) * 256 + kn, &Bs[cur ^ 1][p * 2048 + ldst]);
            }
        }
        const short* Ab = As[cur];
        const short* Bb = Bs[cur];
#pragma unroll
        for (int h = 0; h < 2; ++h) {
            bf16x8 af[4], bfr[4];
#pragma unroll
            for (int i = 0; i < 4; ++i)
                af[i] = *(const bf16x8*)&Bb[(wm + i * 16 + frow) * 64 + ((h * 4 + quad) ^ sw) * 8];
#pragma unroll
            for (int j = 0; j < 4; ++j)
                bfr[j] = *(const bf16x8*)&Ab[(wn + j * 16 + frow) * 64 + ((h * 4 + quad) ^ sw) * 8];
#pragma unroll
            for (int i = 0; i < 4; ++i)
#pragma unroll
                for (int j = 0; j < 4; ++j)
                    acc[i][j] = __builtin_amdgcn_mfma_f32_16x16x32_bf16(af[i], bfr[j], acc[i][j], 0, 0, 0);
        }
        __syncthreads();
        cur ^= 1;
    }
    // epilogue: lane holds 4 consecutive s per (i,j) -> float4 stores
    float* ob = out + (size_t)n * 256 * HWB;
#pragma unroll
    for (int i = 0; i < 4; ++i) {
        const int sLoc0 = wm + i * 16 + quad * 4;
        const int s0 = tileS + sLoc0;
        if (s0 >= HWB) continue;
        float4 t7v = *(const float4*)&t7loc[sLoc0];
#pragma unroll
        for (int j = 0; j < 4; ++j) {
            const int a = tileA + wn + j * 16 + frow;
            float4 o;
            o.x = acc[i][j][0] * 0.0625f + t7v.x;
            o.y = acc[i][j][1] * 0.0625f + t7v.y;
            o.z = acc[i][j][2] * 0.0625f + t7v.z;
            o.w = acc[i][j][3] * 0.0625f + t7v.w;
            *(float4*)&ob[(size_t)a * HWB + s0] = o;
        }
    }
}

extern "C" void kernel_launch(void* const* d_in, const int* in_sizes, int n_in,
                              void* d_out, int out_size, void* d_ws, size_t ws_size,
                              hipStream_t stream) {
    const float* x  = (const float*)d_in[0];
    const float* p1 = (const float*)d_in[1];
    const float* cw = (const float*)d_in[2];
    const float* p4 = (const float*)d_in[3];
    const float* p5 = (const float*)d_in[4];

    char* w = (char*)d_ws;
    unsigned short* xp    = (unsigned short*)w;  w += (size_t)32 * SPAD * 256 * 2;   // 55.1 MB
    unsigned short* t3cl  = (unsigned short*)w;  w += (size_t)32 * HWPAD * 256 * 2;  // 52.4 MB
    unsigned short* p1t   = (unsigned short*)w;  w += (size_t)256 * HWB * 2;
    unsigned short* wpack = (unsigned short*)w;  w += (size_t)256 * 1152 * 2;
    unsigned short* t4h   = (unsigned short*)w;  w += (size_t)8192 * 256 * 2;
    float* t5             = (float*)w;           w += (size_t)8192 * 4;

    // d_out doubles as scratch; xc's only consumer (k_mfma) finishes before
    // k_bmm overwrites d_out:  xc [32][256][3136] bf16 = 51.4 MB <= 102.8 MB
    char* o = (char*)d_out;
    unsigned short* xc = (unsigned short*)o;
    float* out = (float*)d_out;

    k_prep <<<dim3(8248), 256, 0, stream>>>(x, xc, xp, p1, cw, p1t, wpack, t5);
    k_mfma <<<dim3(1728), 256, 0, stream>>>(xp, wpack, t3cl, xc, p1t, p4, p5, t4h, t5);
    k_bmm  <<<dim3(1600), 256, 0, stream>>>(t4h, t3cl, xp, t5, out);
}

// Round 10
// 321.085 us; speedup vs baseline: 1.0162x; 1.0162x over previous
//
#include <hip/hip_runtime.h>

#define HWB   3136
#define HWPAD 3200
#define SPAD  3364   // 58*58 zero-padded spatial

typedef __attribute__((ext_vector_type(8))) short bf16x8;
typedef __attribute__((ext_vector_type(4))) float f32x4;

__device__ __forceinline__ unsigned short f2bf(float f) {
    unsigned u = __float_as_uint(f);
    unsigned r = (u + 0x7fffu + ((u >> 16) & 1u)) >> 16;
    return (unsigned short)r;
}
__device__ __forceinline__ float bf2f(unsigned short h) {
    return __uint_as_float(((unsigned)h) << 16);
}
__device__ __forceinline__ void gl_lds16(const void* g, void* l) {
    __builtin_amdgcn_global_load_lds(
        (const __attribute__((address_space(1))) void*)g,
        (__attribute__((address_space(3))) void*)l, 16, 0, 0);
}

// ---------------------------------------------------------------------------
// Merged prep (one dispatch, 8248 blocks):
//  [0,6272):    x f32 -> xc bf16 (same layout) + xp bf16 (padded ch-last).
//  [6272,7056): p1 -> p1t transpose.  [7056,7312): wpack.
//  [7312,8240): xp border zero.  [8240,8248): zero t5.
// ---------------------------------------------------------------------------
__global__ __launch_bounds__(256) void k_prep(
    const float* __restrict__ x, unsigned short* __restrict__ xc,
    unsigned short* __restrict__ xp,
    const float* __restrict__ p1, const float* __restrict__ cw,
    unsigned short* __restrict__ p1t, unsigned short* __restrict__ wp,
    float* __restrict__ t5)
{
    const int b = blockIdx.x, t = threadIdx.x;
    if (b < 6272) {
        __shared__ unsigned tile[64 * 33];     // dwords = channel pairs
        const int n = b / 196, rem = b - n * 196;
        const int c0 = (rem / 49) * 64, s0 = (rem % 49) * 64;
        const int cp = t >> 3;                 // 0..31 channel pair
        const int sg = (t & 7) * 8;            // s offset within tile

        const float* src = x + ((size_t)(n * 256 + c0 + 2 * cp)) * HWB + s0 + sg;
        unsigned short b0[8], b1[8];
        {
            float4 v0 = *(const float4*)(src);
            float4 v1 = *(const float4*)(src + 4);
            float4 w0 = *(const float4*)(src + HWB);
            float4 w1 = *(const float4*)(src + HWB + 4);
            b0[0] = f2bf(v0.x); b0[1] = f2bf(v0.y); b0[2] = f2bf(v0.z); b0[3] = f2bf(v0.w);
            b0[4] = f2bf(v1.x); b0[5] = f2bf(v1.y); b0[6] = f2bf(v1.z); b0[7] = f2bf(v1.w);
            b1[0] = f2bf(w0.x); b1[1] = f2bf(w0.y); b1[2] = f2bf(w0.z); b1[3] = f2bf(w0.w);
            b1[4] = f2bf(w1.x); b1[5] = f2bf(w1.y); b1[6] = f2bf(w1.z); b1[7] = f2bf(w1.w);
        }
        unsigned short* xcb = xc + ((size_t)(n * 256 + c0 + 2 * cp)) * HWB + s0 + sg;
        *(bf16x8*)xcb = *(const bf16x8*)&b0[0];
        *(bf16x8*)(xcb + HWB) = *(const bf16x8*)&b1[0];
#pragma unroll
        for (int k = 0; k < 8; ++k)
            tile[(sg + k) * 33 + cp] = (unsigned)b0[k] | ((unsigned)b1[k] << 16);
        __syncthreads();
        const int r = t >> 2;                  // 0..63 local s row
        const int cq = (t & 3) * 8;            // dword col base
        unsigned d[8];
#pragma unroll
        for (int j = 0; j < 8; ++j)
            d[j] = tile[r * 33 + cq + j];
        const int s = s0 + r;
        const int sp = s + 2 * (s / 56) + 59;  // (y+1)*58 + (x+1)
        unsigned* dst = (unsigned*)(xp + ((size_t)n * SPAD + sp) * 256 + c0 + 2 * cq);
        *(uint4*)dst = make_uint4(d[0], d[1], d[2], d[3]);
        *(uint4*)(dst + 4) = make_uint4(d[4], d[5], d[6], d[7]);
    } else if (b < 7056) {
        __shared__ unsigned short tile[32][33];
        const int b2 = b - 6272;
        const int h0 = (b2 % 98) * 32, e0 = (b2 / 98) * 32;
        const int lx = t & 31, ly = t >> 5;
#pragma unroll
        for (int it = 0; it < 4; ++it) {
            int lh = ly + it * 8;
            tile[lh][lx] = f2bf(p1[(size_t)(h0 + lh) * 256 + e0 + lx]);
        }
        __syncthreads();
#pragma unroll
        for (int it = 0; it < 4; ++it) {
            int le = ly + it * 8;
            p1t[(size_t)(e0 + le) * HWB + h0 + lx] = tile[lx][le];
        }
    } else if (b < 7312) {
        const int o = b - 7056;
#pragma unroll
        for (int k = t; k < 1152; k += 256) {
            int tap = k >> 7, ci = k & 127;
            wp[(size_t)o * 1152 + k] = f2bf(cw[(size_t)o * 1152 + ci * 9 + tap]);
        }
    } else if (b < 8240) {
        const int bb = b - 7312;
        const int n = bb / 29, xb = bb - n * 29;
        const int idx = xb * 256 + t;
        if (idx < 228 * 32) {
            const int i = idx >> 5, ch = idx & 31;
            int sp;
            if (i < 58)       sp = i;
            else if (i < 116) sp = 3306 + (i - 58);
            else if (i < 172) sp = (i - 115) * 58;
            else              sp = (i - 171) * 58 + 57;
            bf16x8 z = {};
            *(bf16x8*)&xp[((size_t)n * SPAD + sp) * 256 + ch * 8] = z;
        }
    } else {
        float4 z = {0.f, 0.f, 0.f, 0.f};
        *(float4*)&t5[(((b - 8240) * 256) + t) * 4] = z;
    }
}

// ---------------------------------------------------------------------------
// Merged MFMA dispatch (1728 blocks):
//  [0,128):     GEMM1 split-K=1 (K=3136, 49 steps) with FUSED t4scale
//               epilogue: t4h[m][e] = bf16(acc*p4), t5[m] += partial (atomic;
//               exactly 2 commutative adds per entry -> deterministic).
//               Placed FIRST so the long-K blocks start at t=0.
//  [128,1728):  grouped 3x3 conv GEMM per (n,g), K=1152, XCD-swizzled,
//               double-buffered LDS (the proven 76/92us kernel, unchanged).
// ---------------------------------------------------------------------------
__global__ __launch_bounds__(256) void k_mfma(
    const unsigned short* __restrict__ xp, const unsigned short* __restrict__ wp,
    unsigned short* __restrict__ t3cl,
    const unsigned short* __restrict__ xc, const unsigned short* __restrict__ p1t,
    const float* __restrict__ p4, const float* __restrict__ p5,
    unsigned short* __restrict__ t4h, float* __restrict__ t5)
{
    __shared__ short As[2][128 * 64];
    __shared__ short Bs[2][128 * 64];
    const int tid = threadIdx.x;
    const int wave = tid >> 6, lane = tid & 63;
    const int wm = (wave >> 1) * 64, wn = (wave & 1) * 64;
    const int rl = tid >> 3, q = tid & 7;
    const int swq = (q ^ (rl & 7)) * 8;
    const int ldst = rl * 64 + q * 8;
    const int frow = lane & 15, quad = lane >> 4, sw = frow & 7;

    if (blockIdx.x >= 128) {
        // ----- conv -----
        const int orig = blockIdx.x - 128;                 // 1600 = 8 * 200
        const int wgid = (orig & 7) * 200 + (orig >> 3);
        const int ng = wgid / 25;
        const int tileS = (wgid - ng * 25) * 128;
        const int n = ng >> 1, g = ng & 1;

        const unsigned short* xpn = xp + (size_t)n * SPAD * 256 + g * 128 + swq;
        const unsigned short* arow[4];
        const unsigned short* brow[4];
#pragma unroll
        for (int p = 0; p < 4; ++p) {
            int s = tileS + p * 32 + rl;
            int sc = s < HWB ? s : HWB - 1;
            int sp = sc + 2 * (sc / 56) + 59;
            arow[p] = xpn + (size_t)sp * 256;
            brow[p] = wp + (size_t)(g * 128 + p * 32 + rl) * 1152 + swq;
        }

        f32x4 acc[4][4] = {};
        int rofA[4], rofB[4];
#pragma unroll
        for (int i = 0; i < 4; ++i) {
            rofA[i] = (wm + i * 16 + frow) * 64;
            rofB[i] = (wn + i * 16 + frow) * 64;
        }
        {
            const int shift0 = (-59) * 256;
#pragma unroll
            for (int p = 0; p < 4; ++p) {
                gl_lds16(arow[p] + shift0, &As[0][p * 2048 + ldst]);
                gl_lds16(brow[p], &Bs[0][p * 2048 + ldst]);
            }
        }
        __syncthreads();

        int cur = 0;
#pragma unroll
        for (int t = 0; t < 18; ++t) {
            if (t < 17) {
                const int tn = t + 1;
                const int tap = tn >> 1;
                const int shift = ((tap / 3 - 1) * 58 + (tap % 3 - 1)) * 256 + (tn & 1) * 64;
#pragma unroll
                for (int p = 0; p < 4; ++p) {
                    gl_lds16(arow[p] + shift, &As[cur ^ 1][p * 2048 + ldst]);
                    gl_lds16(brow[p] + tn * 64, &Bs[cur ^ 1][p * 2048 + ldst]);
                }
            }
            const short* Ab = As[cur];
            const short* Bb = Bs[cur];
#pragma unroll
            for (int h = 0; h < 2; ++h) {
                bf16x8 af[4], bfr[4];
#pragma unroll
                for (int i = 0; i < 4; ++i)
                    af[i] = *(const bf16x8*)&Ab[rofA[i] + ((h * 4 + quad) ^ sw) * 8];
#pragma unroll
                for (int j = 0; j < 4; ++j)
                    bfr[j] = *(const bf16x8*)&Bb[rofB[j] + ((h * 4 + quad) ^ sw) * 8];
#pragma unroll
                for (int i = 0; i < 4; ++i)
#pragma unroll
                    for (int j = 0; j < 4; ++j)
                        acc[i][j] = __builtin_amdgcn_mfma_f32_16x16x32_bf16(af[i], bfr[j], acc[i][j], 0, 0, 0);
            }
            __syncthreads();
            cur ^= 1;
        }
        unsigned short* ob = t3cl + (size_t)n * HWPAD * 256 + g * 128;
#pragma unroll
        for (int i = 0; i < 4; ++i)
#pragma unroll
            for (int r = 0; r < 4; ++r) {
                int s = tileS + wm + i * 16 + quad * 4 + r;
                int c = wn + frow;
#pragma unroll
                for (int j = 0; j < 4; ++j) {
                    float v = (s < HWB) ? acc[i][j][r] : 0.f;
                    ob[(size_t)s * 256 + c + j * 16] = f2bf(v);
                }
            }
    } else {
        // ----- gemm1 (split-K=1, fused t4scale epilogue) -----
        const int orig = blockIdx.x;                      // 128 = 8 * 16
        const int wgid = (orig & 7) * 16 + (orig >> 3);
        const int tileM = (wgid >> 1) * 128;
        const int tileN = (wgid & 1) * 128;

        const unsigned short* asrc = xc + (size_t)(tileM + rl) * HWB + swq;
        const unsigned short* bsrc = p1t + (size_t)(tileN + rl) * HWB + swq;

        f32x4 acc[4][4] = {};
#pragma unroll
        for (int p = 0; p < 4; ++p) {
            gl_lds16(asrc + (size_t)(p * 32) * HWB, &As[0][p * 2048 + ldst]);
            gl_lds16(bsrc + (size_t)(p * 32) * HWB, &Bs[0][p * 2048 + ldst]);
        }
        __syncthreads();

        int cur = 0;
        for (int i2 = 0; i2 < 49; ++i2) {
            if (i2 + 1 < 49) {
                const int kn = (i2 + 1) * 64;
#pragma unroll
                for (int p = 0; p < 4; ++p) {
                    gl_lds16(asrc + (size_t)(p * 32) * HWB + kn, &As[cur ^ 1][p * 2048 + ldst]);
                    gl_lds16(bsrc + (size_t)(p * 32) * HWB + kn, &Bs[cur ^ 1][p * 2048 + ldst]);
                }
            }
            const short* Ab = As[cur];
            const short* Bb = Bs[cur];
#pragma unroll
            for (int h = 0; h < 2; ++h) {
                bf16x8 af[4], bfr[4];
#pragma unroll
                for (int i = 0; i < 4; ++i)
                    af[i] = *(const bf16x8*)&Ab[(wm + i * 16 + frow) * 64 + ((h * 4 + quad) ^ sw) * 8];
#pragma unroll
                for (int j = 0; j < 4; ++j)
                    bfr[j] = *(const bf16x8*)&Bb[(wn + j * 16 + frow) * 64 + ((h * 4 + quad) ^ sw) * 8];
#pragma unroll
                for (int i = 0; i < 4; ++i)
#pragma unroll
                    for (int j = 0; j < 4; ++j)
                        acc[i][j] = __builtin_amdgcn_mfma_f32_16x16x32_bf16(af[i], bfr[j], acc[i][j], 0, 0, 0);
            }
            __syncthreads();
            cur ^= 1;
        }
        // fused t4scale: t4h = bf16(acc*p4); t5[m] += sum_e t4*p5 (partial)
        float p5v[4];
#pragma unroll
        for (int j = 0; j < 4; ++j)
            p5v[j] = p5[tileN + wn + j * 16 + frow];
#pragma unroll
        for (int i = 0; i < 4; ++i)
#pragma unroll
            for (int r = 0; r < 4; ++r) {
                const int m = tileM + wm + i * 16 + quad * 4 + r;
                const float* p4row = p4 + (size_t)(m & 255) * 256;
                float s = 0.f;
#pragma unroll
                for (int j = 0; j < 4; ++j) {
                    const int e = tileN + wn + j * 16 + frow;
                    const float t4v = acc[i][j][r] * p4row[e];
                    t4h[(size_t)m * 256 + e] = f2bf(t4v);
                    s += t4v * p5v[j];
                }
#pragma unroll
                for (int off = 1; off < 16; off <<= 1)
                    s += __shfl_xor(s, off);
                if (frow == 0) atomicAdd(&t5[m], s);
            }
    }
}

// ---------------------------------------------------------------------------
// BMM: out[n][a][s] = (sum_b t4h[n][a][b] * t3cl[n][s][b]) / 16 + t7[n][s]
// t7 computed in-kernel from xp row dot t5 (4 ILP chains).
// XCD-swizzled grid; double-buffered staging.
// ---------------------------------------------------------------------------
__global__ __launch_bounds__(256) void k_bmm(
    const unsigned short* __restrict__ t4h, const unsigned short* __restrict__ t3cl,
    const unsigned short* __restrict__ xp, const float* __restrict__ t5,
    float* __restrict__ out)
{
    __shared__ short As[2][128 * 64];
    __shared__ short Bs[2][128 * 64];
    __shared__ float t5s[256];
    __shared__ float t7loc[128];
    const int tid = threadIdx.x;
    const int orig = blockIdx.x;                       // 1600 = 8 * 200
    const int wgid = (orig & 7) * 200 + (orig >> 3);
    const int n = wgid / 50;
    const int rem = wgid - n * 50;
    const int tileA = (rem / 25) * 128;
    const int tileS = (rem % 25) * 128;
    const int wave = tid >> 6, lane = tid & 63;
    const int wm = (wave >> 1) * 64, wn = (wave & 1) * 64;

    const int rl = tid >> 3, q = tid & 7;
    const int swq = (q ^ (rl & 7)) * 8;
    const unsigned short* asrc = t4h + ((size_t)n * 256 + tileA + rl) * 256 + swq;
    const unsigned short* bsrc = t3cl + ((size_t)n * HWPAD + tileS + rl) * 256 + swq;

    f32x4 acc[4][4] = {};
    const int frow = lane & 15, quad = lane >> 4, sw = frow & 7;
    const int ldst = rl * 64 + q * 8;

    t5s[tid] = t5[n * 256 + tid];
#pragma unroll
    for (int p = 0; p < 4; ++p) {
        gl_lds16(asrc + (size_t)(p * 32) * 256, &As[0][p * 2048 + ldst]);
        gl_lds16(bsrc + (size_t)(p * 32) * 256, &Bs[0][p * 2048 + ldst]);
    }
    __syncthreads();   // t5s visible; buf0 staged

    if (tid < 128) {
        const int s = tileS + tid;
        float accv = 0.f;
        if (s < HWB) {
            const int sp = s + 2 * (s / 56) + 59;
            const unsigned short* row = xp + ((size_t)n * SPAD + sp) * 256;
            float p0 = 0.f, p1 = 0.f, p2 = 0.f, p3 = 0.f;
#pragma unroll
            for (int j = 0; j < 32; ++j) {
                bf16x8 v = *(const bf16x8*)(row + j * 8);
                p0 += t5s[j * 8 + 0] * bf2f((unsigned short)v[0]);
                p1 += t5s[j * 8 + 1] * bf2f((unsigned short)v[1]);
                p2 += t5s[j * 8 + 2] * bf2f((unsigned short)v[2]);
                p3 += t5s[j * 8 + 3] * bf2f((unsigned short)v[3]);
                p0 += t5s[j * 8 + 4] * bf2f((unsigned short)v[4]);
                p1 += t5s[j * 8 + 5] * bf2f((unsigned short)v[5]);
                p2 += t5s[j * 8 + 6] * bf2f((unsigned short)v[6]);
                p3 += t5s[j * 8 + 7] * bf2f((unsigned short)v[7]);
            }
            accv = (p0 + p1) + (p2 + p3);
        }
        t7loc[tid] = accv * 0.0625f;
    }

    int cur = 0;
#pragma unroll
    for (int k0 = 0; k0 < 256; k0 += 64) {
        if (k0 < 192) {
            const int kn = k0 + 64;
#pragma unroll
            for (int p = 0; p < 4; ++p) {
                gl_lds16(asrc + (size_t)(p * 32) * 256 + kn, &As[cur ^ 1][p * 2048 + ldst]);
                gl_lds16(bsrc + (size_t)(p * 32) * 256 + kn, &Bs[cur ^ 1][p * 2048 + ldst]);
            }
        }
        const short* Ab = As[cur];
        const short* Bb = Bs[cur];
#pragma unroll
        for (int h = 0; h < 2; ++h) {
            bf16x8 af[4], bfr[4];
#pragma unroll
            for (int i = 0; i < 4; ++i)
                af[i] = *(const bf16x8*)&Ab[(wm + i * 16 + frow) * 64 + ((h * 4 + quad) ^ sw) * 8];
#pragma unroll
            for (int j = 0; j < 4; ++j)
                bfr[j] = *(const bf16x8*)&Bb[(wn + j * 16 + frow) * 64 + ((h * 4 + quad) ^ sw) * 8];
#pragma unroll
            for (int i = 0; i < 4; ++i)
#pragma unroll
                for (int j = 0; j < 4; ++j)
                    acc[i][j] = __builtin_amdgcn_mfma_f32_16x16x32_bf16(af[i], bfr[j], acc[i][j], 0, 0, 0);
        }
        __syncthreads();
        cur ^= 1;
    }
    float* ob = out + (size_t)n * 256 * HWB;
#pragma unroll
    for (int j = 0; j < 4; ++j) {
        const int sLoc = wn + j * 16 + frow;
        const int s = tileS + sLoc;
        if (s >= HWB) continue;
        const float t7v = t7loc[sLoc];
#pragma unroll
        for (int i = 0; i < 4; ++i)
#pragma unroll
            for (int r = 0; r < 4; ++r) {
                int a = tileA + wm + i * 16 + quad * 4 + r;
                ob[(size_t)a * HWB + s] = acc[i][j][r] * 0.0625f + t7v;
            }
    }
}

extern "C" void kernel_launch(void* const* d_in, const int* in_sizes, int n_in,
                              void* d_out, int out_size, void* d_ws, size_t ws_size,
                              hipStream_t stream) {
    const float* x  = (const float*)d_in[0];
    const float* p1 = (const float*)d_in[1];
    const float* cw = (const float*)d_in[2];
    const float* p4 = (const float*)d_in[3];
    const float* p5 = (const float*)d_in[4];

    char* w = (char*)d_ws;
    unsigned short* xp    = (unsigned short*)w;  w += (size_t)32 * SPAD * 256 * 2;   // 55.1 MB
    unsigned short* t3cl  = (unsigned short*)w;  w += (size_t)32 * HWPAD * 256 * 2;  // 52.4 MB
    unsigned short* p1t   = (unsigned short*)w;  w += (size_t)256 * HWB * 2;
    unsigned short* wpack = (unsigned short*)w;  w += (size_t)256 * 1152 * 2;
    unsigned short* t4h   = (unsigned short*)w;  w += (size_t)8192 * 256 * 2;
    float* t5             = (float*)w;           w += (size_t)8192 * 4;

    // d_out doubles as scratch; xc's only consumer (k_mfma) finishes before
    // k_bmm overwrites d_out:  xc [32][256][3136] bf16 = 51.4 MB <= 102.8 MB
    char* o = (char*)d_out;
    unsigned short* xc = (unsigned short*)o;
    float* out = (float*)d_out;

    k_prep <<<dim3(8248), 256, 0, stream>>>(x, xc, xp, p1, cw, p1t, wpack, t5);
    k_mfma <<<dim3(1728), 256, 0, stream>>>(xp, wpack, t3cl, xc, p1t, p4, p5, t4h, t5);
    k_bmm  <<<dim3(1600), 256, 0, stream>>>(t4h, t3cl, xp, t5, out);
}